// Round 17
// baseline (256.079 us; speedup 1.0000x reference)
//
#include <hip/hip_runtime.h>

// ---------------------------------------------------------------------------
// Local windowed attention, B=8 N=8192 D=512, WS=128, lookback=1.
//   k_cvt : fp32 -> bf16 convert of x and weights (scratch in d_out).
//   k_qkv : merged Q/K/V projection GEMM, r6 structure scaled to 512 thr /
//           BM=256 (8 waves 4mx2n): 80KB LDS -> 2 blocks/CU = 16 waves/CU
//           (2x r6's TLP to hide the barrier drain), 10 loads/thr/K-step.
//           Q,K row-major bf16; V in Vt3[b][key/32][dv][key%32] (no swizzle).
//   k_attn: r12 form (best measured): per (b,window), 8 waves x 16 q-rows,
//           Q in regs, K staged in LDS, per-wave softmax, P in wave-private
//           LDS, V staged via Vt3, deferred normalization.
// ---------------------------------------------------------------------------

typedef __bf16 bf16x8 __attribute__((ext_vector_type(8)));
typedef float f32x4 __attribute__((ext_vector_type(4)));
typedef unsigned short u16x8 __attribute__((ext_vector_type(8)));

#define BATCH 8
#define SEQ   8192
#define DIM   512
#define NWIN  64
#define TOKS  (BATCH * SEQ)          // 65536
#define WSELEM ((size_t)TOKS * DIM)  // 33554432 elements per Q/K/V buffer

__device__ __forceinline__ unsigned short f2b(float f) {
    union { float f; unsigned int u; } c; c.f = f;
    unsigned int u = c.u;
    return (unsigned short)((u + 0x7FFFu + ((u >> 16) & 1u)) >> 16);
}

// XOR swizzle for [rows][64]-ushort LDS tiles (128B rows).
__device__ __forceinline__ int swz64(int row, int col) {
    return (row * 64 + col) ^ ((row & 7) << 3);
}

__device__ __forceinline__ void gload_lds16(const void* g, void* l) {
    __builtin_amdgcn_global_load_lds(
        (const __attribute__((address_space(1))) void*)g,
        (__attribute__((address_space(3))) void*)l, 16, 0, 0);
}

// ===========================================================================
// Kernel 0: fp32 -> bf16 bulk convert
// ===========================================================================
__global__ __launch_bounds__(256) void k_cvt(const float* __restrict__ s,
                                             unsigned short* __restrict__ d,
                                             int n8) {
    const int stride = gridDim.x * blockDim.x;
    for (int i = blockIdx.x * blockDim.x + threadIdx.x; i < n8; i += stride) {
        const float4 a = ((const float4*)s)[2 * i];
        const float4 b = ((const float4*)s)[2 * i + 1];
        u16x8 v;
        v[0] = f2b(a.x); v[1] = f2b(a.y); v[2] = f2b(a.z); v[3] = f2b(a.w);
        v[4] = f2b(b.x); v[5] = f2b(b.y); v[6] = f2b(b.z); v[7] = f2b(b.w);
        ((u16x8*)d)[i] = v;
    }
}

// ===========================================================================
// Kernel 1: merged QKV projection GEMM, BM=256. grid = 256*4 = 1024,
// block = 512 (8 waves, 4m x 2n, wave tile 64x64 x 3 ops).
// LDS: X[256][64] 32KB | Wq|Wk|Wv [128][64] 16KB each = 80KB -> 2 blk/CU.
// Per K-step: 10 gload_lds(16B)/thread, 96 MFMA/wave, 2 barriers.
// ===========================================================================
__global__ __launch_bounds__(512, 2) void k_qkv(
    const unsigned short* __restrict__ xb, const unsigned short* __restrict__ wb,
    const float* __restrict__ bq, const float* __restrict__ bk,
    const float* __restrict__ bv,
    unsigned short* __restrict__ qo, unsigned short* __restrict__ ko,
    unsigned short* __restrict__ vto)
{
    __shared__ __align__(16) unsigned short sm[40960]; // Xs 16384 | W0|W1|W2 8192 each; V-epi T[256][129] aliases
    unsigned short* Xs = sm;

    int bid = (int)blockIdx.x;
    bid = (bid & 7) * 128 + (bid >> 3);   // XCD-contiguous chunks (1024 % 8 == 0)
    const int mt = bid >> 2, nt = bid & 3;
    const int rbase = mt << 8;            // token row base (mult of 256)
    const int cbase = nt << 7;            // output feature base

    const unsigned short* __restrict__ xsrc0 = xb + ((size_t)rbase << 9);
    const unsigned short* __restrict__ wsrc0 = wb + ((size_t)cbase << 9);

    const int tid  = threadIdx.x;
    const int lane = tid & 63;
    const int wid  = tid >> 6;
    const int wm = wid >> 1, wn = wid & 1;   // 4m x 2n wave grid
    const int l15 = lane & 15, lg = lane >> 4;

    f32x4 acc[3][4][4];
#pragma unroll
    for (int s = 0; s < 3; ++s)
#pragma unroll
        for (int m = 0; m < 4; ++m)
#pragma unroll
            for (int n = 0; n < 4; ++n) acc[s][m][n] = (f32x4){0.f, 0.f, 0.f, 0.f};

    for (int ks = 0; ks < 8; ++ks) {
        const int kc = ks << 6;
        // ---- stage X (4 slots/thr) + 3 W tiles (2 slots/thr each)
#pragma unroll
        for (int i = 0; i < 4; ++i) {
            const int s = (i << 9) + tid;          // slot 0..2047
            const int row = s >> 3, sl = s & 7;
            gload_lds16(xsrc0 + ((size_t)row << 9) + kc + ((sl ^ (row & 7)) << 3),
                        Xs + (s << 3));
        }
#pragma unroll
        for (int ws = 0; ws < 3; ++ws) {
#pragma unroll
            for (int i = 0; i < 2; ++i) {
                const int s = (i << 9) + tid;      // slot 0..1023
                const int row = s >> 3, sl = s & 7;
                gload_lds16(wsrc0 + ((size_t)ws << 18) + ((size_t)row << 9)
                                + kc + ((sl ^ (row & 7)) << 3),
                            sm + 16384 + (ws << 13) + (s << 3));
            }
        }
        __syncthreads();
        // ---- 96 MFMA/wave on the 64-wide K chunk (af reused across 3 ops)
#pragma unroll
        for (int kk = 0; kk < 64; kk += 32) {
            const int cu = kk + (lg << 3);
            bf16x8 af[4];
#pragma unroll
            for (int m = 0; m < 4; ++m)
                af[m] = *(const bf16x8*)&Xs[swz64((wm << 6) + (m << 4) + l15, cu)];
#pragma unroll
            for (int ws = 0; ws < 3; ++ws) {
                const unsigned short* Wsb = sm + 16384 + (ws << 13);
                bf16x8 bfr[4];
#pragma unroll
                for (int n = 0; n < 4; ++n)
                    bfr[n] = *(const bf16x8*)&Wsb[swz64((wn << 6) + (n << 4) + l15, cu)];
#pragma unroll
                for (int m = 0; m < 4; ++m)
#pragma unroll
                    for (int n = 0; n < 4; ++n)
                        acc[ws][m][n] = __builtin_amdgcn_mfma_f32_16x16x32_bf16(
                            af[m], bfr[n], acc[ws][m][n], 0, 0, 0);
            }
        }
        __syncthreads();
    }

    // ---- Q/K epilogues: row-major bf16 stores (rows 0..255)
#pragma unroll
    for (int ws = 0; ws < 2; ++ws) {
        unsigned short* __restrict__ out = ws ? ko : qo;
        const float* __restrict__ bias = ws ? bk : bq;
#pragma unroll
        for (int n = 0; n < 4; ++n) {
            const int col = cbase + (wn << 6) + (n << 4) + l15;
            const float bv_ = bias[col];
#pragma unroll
            for (int m = 0; m < 4; ++m)
#pragma unroll
                for (int j = 0; j < 4; ++j) {
                    const int row = rbase + (wm << 6) + (m << 4) + (lg << 2) + j;
                    out[(size_t)row * DIM + col] = f2b(acc[ws][m][n][j] + bv_);
                }
        }
    }
    // ---- V epilogue: transpose via LDS T[256][129], then wave-contiguous
    //      1KB stores to Vt3[b][key/32][dv][key%32] (r7-verified map)
#pragma unroll
    for (int n = 0; n < 4; ++n) {
        const int dv = (wn << 6) + (n << 4) + l15;
        const float bv_ = bv[cbase + dv];
#pragma unroll
        for (int m = 0; m < 4; ++m)
#pragma unroll
            for (int j = 0; j < 4; ++j) {
                const int tok = (wm << 6) + (m << 4) + (lg << 2) + j;   // 0..255
                sm[tok * 129 + dv] = f2b(acc[2][m][n][j] + bv_);
            }
    }
    __syncthreads();
    {
        const int batch = rbase >> 13;
        const int c5_0  = (rbase & 8191) >> 5;   // key-chunk base (mult of 8)
        const int dvl   = tid >> 2;              // 0..127
        const int keyo  = (tid & 3) << 3;        // 0,8,16,24 (ushorts)
#pragma unroll
        for (int s = 0; s < 8; ++s) {
            const int tok0 = (s << 5) + keyo;
            u16x8 v;
#pragma unroll
            for (int j = 0; j < 8; ++j) v[j] = sm[(tok0 + j) * 129 + dvl];
            *(u16x8*)&vto[((size_t)((batch * 256 + c5_0 + s) * 512
                                    + cbase + dvl) << 5) + keyo] = v;
        }
    }
}

// ===========================================================================
// Kernel 2: windowed attention (r12 form). grid = 512 x 512thr (8 waves).
// Wave w owns q-rows [w*16, w*16+16); Q in regs; K staged; V via Vt3.
// ===========================================================================
__global__ __launch_bounds__(512, 2) void k_attn(
    const unsigned short* __restrict__ q,
    const unsigned short* __restrict__ k,
    const unsigned short* __restrict__ vt3,
    float* __restrict__ out)
{
    __shared__ __align__(16) unsigned short Kb[32768];
    __shared__ __align__(16) unsigned short Pl[32768];

    int bid = (int)blockIdx.x;
    bid = (bid & 7) * 64 + (bid >> 3);    // XCD-chunked: one batch per XCD
    const int b = bid >> 6, w = bid & 63;
    const int tid  = threadIdx.x;
    const int lane = tid & 63, wid = tid >> 6;
    const int l15 = lane & 15, lg = lane >> 4;
    const int kstart = (w - 1) << 7;
    const size_t qrow0 = ((size_t)b << 13) + ((size_t)w << 7);
    const size_t kbase = (size_t)b << 13;

    const int srow = tid >> 3;            // 0..63
    const int s0   = tid & 7;

    // ---------------- Q-hoist: 16 bf16x8 frags -----------------------------
    bf16x8 qreg[16];
    {
        const unsigned short* qrp =
            &q[(qrow0 + (wid << 4) + l15) * DIM + (lg << 3)];
#pragma unroll
        for (int i = 0; i < 16; ++i)
            qreg[i] = *(const bf16x8*)&qrp[i << 5];
    }

    // ---------------- phase A: S = Q K^T (per-wave 16 x 256, inner 512) -----
    f32x4 acc[16];
#pragma unroll
    for (int n = 0; n < 16; ++n) acc[n] = (f32x4){0.f, 0.f, 0.f, 0.f};

    auto stageK = [&](int buf, int ds) {
#pragma unroll
        for (int i = 0; i < 4; ++i) {
            const int r = (i << 6) + srow;
            int krow = kstart + r; krow = krow < 0 ? 0 : krow;  // masked anyway
            gload_lds16(k + (kbase + krow) * DIM + (ds << 6) + ((s0 ^ (r & 7)) << 3),
                        Kb + (buf << 14) + (i << 12) + (tid << 3));
        }
    };

    stageK(0, 0);
    stageK(1, 1);
    __syncthreads();
#pragma unroll
    for (int ds = 0; ds < 8; ++ds) {
        const unsigned short* Kc = Kb + ((ds & 1) << 14);
#pragma unroll
        for (int kk2 = 0; kk2 < 2; ++kk2) {
            const int cu = (kk2 << 5) + (lg << 3);
            const bf16x8 af = qreg[(ds << 1) + kk2];   // static index (unrolled)
#pragma unroll
            for (int n = 0; n < 16; ++n) {
                const bf16x8 bf = *(const bf16x8*)&Kc[swz64((n << 4) + l15, cu)];
                acc[n] = __builtin_amdgcn_mfma_f32_16x16x32_bf16(af, bf, acc[n], 0, 0, 0);
            }
        }
        __syncthreads();
        if (ds + 2 < 8) stageK(ds & 1, ds + 2);  // 1-deep pipeline
    }

    // ---------------- phase B prologue: stage V chunks 0,1 (Kb free now) ----
    const int c5base = kstart >> 5;       // -4 for w==0
    auto stageV = [&](int buf, int kk) {
        int c5 = c5base + kk; c5 = c5 < 0 ? 0 : c5;  // P==0 for those keys
        const unsigned short* src = vt3 + ((size_t)(b * 256 + c5) << 14);
#pragma unroll
        for (int i = 0; i < 4; ++i)
            gload_lds16(src + (i << 12) + (tid << 3),
                        Kb + (buf << 14) + (i << 12) + (tid << 3));
    };
    stageV(0, 0);
    stageV(1, 1);

    // ---------------- per-wave masked softmax (no cross-wave barriers) ------
    const float scale = 0.04419417382415922f;  // 512^-0.5
    float inv[4];
    unsigned short* Pw = Pl + (wid << 12);     // wave-private [16][256] strip
#pragma unroll
    for (int jj = 0; jj < 4; ++jj) {
        const int r  = (lg << 2) + jj;         // wave-local q row
        const int qr = (wid << 4) + r;         // window q row
        float mx = -3.0e38f;
#pragma unroll
        for (int n = 0; n < 16; ++n) {
            const int c = (n << 4) + l15;
            const bool keep = (c <= qr + 128) && (w > 0 || c >= 128);
            const float s = keep ? acc[n][jj] * scale : -INFINITY;
            acc[n][jj] = s;
            mx = fmaxf(mx, s);
        }
#pragma unroll
        for (int o = 1; o < 16; o <<= 1) mx = fmaxf(mx, __shfl_xor(mx, o));
        float sum = 0.f;
#pragma unroll
        for (int n = 0; n < 16; ++n) {
            const float p = __expf(acc[n][jj] - mx);
            acc[n][jj] = p;
            sum += p;
        }
#pragma unroll
        for (int o = 1; o < 16; o <<= 1) sum += __shfl_xor(sum, o);
        inv[jj] = 1.0f / sum;                  // deferred normalization
#pragma unroll
        for (int n = 0; n < 16; ++n) {
            const int c = (n << 4) + l15;
            Pw[(r << 8) + ((((c >> 3) ^ r) << 3) | (c & 7))] = f2b(acc[n][jj]);
        }
    }
    __syncthreads();   // V chunks 0,1 staged; P strips written

    // ---------------- phase B: O = P V (per-wave 16 x 512, inner 256) -------
    f32x4 oacc[32];
#pragma unroll
    for (int n = 0; n < 32; ++n) oacc[n] = (f32x4){0.f, 0.f, 0.f, 0.f};

    for (int kk = 0; kk < 8; ++kk) {
        const unsigned short* Vc = Kb + ((kk & 1) << 14);
        const bf16x8 pa = *(const bf16x8*)
            &Pw[(l15 << 8) + ((((kk << 2) + lg) ^ l15) << 3)];
#pragma unroll
        for (int n = 0; n < 32; ++n) {
            const bf16x8 bv_ = *(const bf16x8*)&Vc[(((n << 4) + l15) << 5) + (lg << 3)];
            oacc[n] = __builtin_amdgcn_mfma_f32_16x16x32_bf16(pa, bv_, oacc[n], 0, 0, 0);
        }
        if (kk < 7) {
            __syncthreads();
            if (kk + 2 < 8) stageV(kk & 1, kk + 2);
        }
    }

    // ---------------- epilogue: normalize and store f32 ---------------------
#pragma unroll
    for (int n = 0; n < 32; ++n) {
        const int dv = (n << 4) + l15;
        float* orow = out + (qrow0 + (wid << 4) + (lg << 2)) * DIM + dv;
#pragma unroll
        for (int jj = 0; jj < 4; ++jj)
            orow[(size_t)jj * DIM] = oacc[n][jj] * inv[jj];
    }
}

// ===========================================================================
extern "C" void kernel_launch(void* const* d_in, const int* in_sizes, int n_in,
                              void* d_out, int out_size, void* d_ws, size_t ws_size,
                              hipStream_t stream) {
    (void)in_sizes; (void)n_in; (void)out_size; (void)ws_size;
    const float* x  = (const float*)d_in[0];
    const float* wq = (const float*)d_in[1];
    const float* bq = (const float*)d_in[2];
    const float* wk = (const float*)d_in[3];
    const float* bk = (const float*)d_in[4];
    const float* wv = (const float*)d_in[5];
    const float* bv = (const float*)d_in[6];
    float* out = (float*)d_out;

    unsigned short* qws  = (unsigned short*)d_ws;
    unsigned short* kws  = qws + WSELEM;
    unsigned short* vtws = kws + WSELEM;

    // xb (64 MiB) + wb (1.5 MiB) live in d_out (128 MiB) — consumed by k_qkv
    // before k_attn overwrites d_out with the final output (stream-ordered).
    unsigned short* xbuf = (unsigned short*)d_out;
    unsigned short* wbuf = xbuf + WSELEM;

    k_cvt<<<2048, 256, 0, stream>>>(x, xbuf, (int)(WSELEM / 8));
    k_cvt<<<128, 256, 0, stream>>>(wq, wbuf, DIM * DIM / 8);
    k_cvt<<<128, 256, 0, stream>>>(wk, wbuf + DIM * DIM, DIM * DIM / 8);
    k_cvt<<<128, 256, 0, stream>>>(wv, wbuf + 2 * DIM * DIM, DIM * DIM / 8);
    k_qkv<<<1024, 512, 0, stream>>>(xbuf, wbuf, bq, bk, bv, qws, kws, vtws);
    k_attn<<<512, 512, 0, stream>>>(qws, kws, vtws, out);
}

// Round 18
// 233.972 us; speedup vs baseline: 1.0945x; 1.0945x over previous
//
#include <hip/hip_runtime.h>

// ---------------------------------------------------------------------------
// Local windowed attention, B=8 N=8192 D=512, WS=128, lookback=1.
//   k_cvt : ONE launch converts x AND wq/wk/wv fp32->bf16 (dst contiguous:
//           xb then wb in d_out). Saves 3 launch overheads vs r6-r17.
//   k_qkv : merged Q/K/V projection GEMM (r6 form — best of 6 variants:
//           133-140us, 775 TF = 85% of the 2-barrier-structure ceiling).
//   k_attn: r12 form (best of 5 variants, ~65us): 8 waves x 16 q-rows,
//           Q hoisted to regs, K staged/dbuf, per-wave softmax, P in
//           wave-private LDS, V staged via Vt3, deferred normalization.
// ---------------------------------------------------------------------------

typedef __bf16 bf16x8 __attribute__((ext_vector_type(8)));
typedef float f32x4 __attribute__((ext_vector_type(4)));
typedef unsigned short u16x8 __attribute__((ext_vector_type(8)));

#define BATCH 8
#define SEQ   8192
#define DIM   512
#define NWIN  64
#define TOKS  (BATCH * SEQ)          // 65536
#define WSELEM ((size_t)TOKS * DIM)  // 33554432 elements per Q/K/V buffer
#define NX8   ((int)(WSELEM / 8))    // 4194304 u16x8 groups in x
#define NW8   (DIM * DIM / 8)        // 32768 groups per weight

__device__ __forceinline__ unsigned short f2b(float f) {
    union { float f; unsigned int u; } c; c.f = f;
    unsigned int u = c.u;
    return (unsigned short)((u + 0x7FFFu + ((u >> 16) & 1u)) >> 16);
}

// XOR swizzle for [rows][64]-ushort LDS tiles (128B rows).
__device__ __forceinline__ int swz64(int row, int col) {
    return (row * 64 + col) ^ ((row & 7) << 3);
}

__device__ __forceinline__ void gload_lds16(const void* g, void* l) {
    __builtin_amdgcn_global_load_lds(
        (const __attribute__((address_space(1))) void*)g,
        (__attribute__((address_space(3))) void*)l, 16, 0, 0);
}

// ===========================================================================
// Kernel 0: fused fp32 -> bf16 convert of x + wq + wk + wv.
// dst is contiguous (xb | wb_q | wb_k | wb_v); src selected per index.
// ===========================================================================
__global__ __launch_bounds__(256) void k_cvt(
    const float* __restrict__ x, const float* __restrict__ wq,
    const float* __restrict__ wk, const float* __restrict__ wv,
    unsigned short* __restrict__ d, int ntot) {
    const int stride = gridDim.x * blockDim.x;
    for (int i = blockIdx.x * blockDim.x + threadIdx.x; i < ntot; i += stride) {
        const float* s;
        size_t off;
        if (i < NX8) { s = x; off = (size_t)i; }
        else {
            const int j = i - NX8;
            const int wsel = j >> 15;           // 0=q 1=k 2=v (NW8 = 32768)
            s = (wsel == 0) ? wq : (wsel == 1) ? wk : wv;
            off = (size_t)(j & (NW8 - 1));
        }
        const float4 a = ((const float4*)s)[2 * off];
        const float4 b = ((const float4*)s)[2 * off + 1];
        u16x8 v;
        v[0] = f2b(a.x); v[1] = f2b(a.y); v[2] = f2b(a.z); v[3] = f2b(a.w);
        v[4] = f2b(b.x); v[5] = f2b(b.y); v[6] = f2b(b.z); v[7] = f2b(b.w);
        ((u16x8*)d)[i] = v;
    }
}

// ===========================================================================
// Kernel 1: merged QKV projection GEMM (r6). grid = 2048, block = 256
// (4 waves, 2x2, wave tile 64x64). X staged once per K-step, reused by 96 MFMA.
// ===========================================================================
__global__ __launch_bounds__(256, 2) void k_qkv(
    const unsigned short* __restrict__ xb, const unsigned short* __restrict__ wb,
    const float* __restrict__ bq, const float* __restrict__ bk,
    const float* __restrict__ bv,
    unsigned short* __restrict__ qo, unsigned short* __restrict__ ko,
    unsigned short* __restrict__ vto)
{
    __shared__ __align__(16) unsigned short sm[32768]; // Xs|Wq|Wk|Wv; V-epi T[128][129] aliases
    unsigned short* Xs = sm;

    int bid = (int)blockIdx.x;
    bid = (bid & 7) * 256 + (bid >> 3);   // XCD-contiguous chunks
    const int mt = bid >> 2, nt = bid & 3;
    const int rbase = mt << 7;            // token row base
    const int cbase = nt << 7;            // output feature base

    const unsigned short* __restrict__ xsrc0 = xb + ((size_t)rbase << 9);
    const unsigned short* __restrict__ wsrc0 = wb + ((size_t)cbase << 9);

    const int tid  = threadIdx.x;
    const int lane = tid & 63;
    const int wid  = tid >> 6;
    const int wm = wid >> 1, wn = wid & 1;
    const int l15 = lane & 15, lg = lane >> 4;

    f32x4 acc[3][4][4];
#pragma unroll
    for (int s = 0; s < 3; ++s)
#pragma unroll
        for (int m = 0; m < 4; ++m)
#pragma unroll
            for (int n = 0; n < 4; ++n) acc[s][m][n] = (f32x4){0.f, 0.f, 0.f, 0.f};

    const int srow = tid >> 3;            // 0..31
    const int gs   = ((tid & 7) ^ (srow & 7)) << 3;  // src 16B slot (swizzled)
    const int ldso = tid << 3;

    for (int ks = 0; ks < 8; ++ks) {
        const int kc = ks << 6;
#pragma unroll
        for (int i = 0; i < 4; ++i) {
            const int row = (i << 5) + srow;
            gload_lds16(xsrc0 + ((size_t)row << 9) + kc + gs, Xs + (i << 11) + ldso);
        }
#pragma unroll
        for (int ws = 0; ws < 3; ++ws) {
#pragma unroll
            for (int i = 0; i < 4; ++i) {
                const int row = (i << 5) + srow;
                gload_lds16(wsrc0 + ((size_t)ws << 18) + ((size_t)row << 9) + kc + gs,
                            sm + 8192 + (ws << 13) + (i << 11) + ldso);
            }
        }
        __syncthreads();
#pragma unroll
        for (int kk = 0; kk < 64; kk += 32) {
            const int cu = kk + (lg << 3);
            bf16x8 af[4];
#pragma unroll
            for (int m = 0; m < 4; ++m)
                af[m] = *(const bf16x8*)&Xs[swz64((wm << 6) + (m << 4) + l15, cu)];
#pragma unroll
            for (int ws = 0; ws < 3; ++ws) {
                const unsigned short* Wsb = sm + 8192 + (ws << 13);
                bf16x8 bfr[4];
#pragma unroll
                for (int n = 0; n < 4; ++n)
                    bfr[n] = *(const bf16x8*)&Wsb[swz64((wn << 6) + (n << 4) + l15, cu)];
#pragma unroll
                for (int m = 0; m < 4; ++m)
#pragma unroll
                    for (int n = 0; n < 4; ++n)
                        acc[ws][m][n] = __builtin_amdgcn_mfma_f32_16x16x32_bf16(
                            af[m], bfr[n], acc[ws][m][n], 0, 0, 0);
            }
        }
        __syncthreads();
    }

    // ---- Q/K epilogues: row-major bf16 stores
#pragma unroll
    for (int ws = 0; ws < 2; ++ws) {
        unsigned short* __restrict__ out = ws ? ko : qo;
        const float* __restrict__ bias = ws ? bk : bq;
#pragma unroll
        for (int n = 0; n < 4; ++n) {
            const int col = cbase + (wn << 6) + (n << 4) + l15;
            const float bv_ = bias[col];
#pragma unroll
            for (int m = 0; m < 4; ++m)
#pragma unroll
                for (int j = 0; j < 4; ++j) {
                    const int row = rbase + (wm << 6) + (m << 4) + (lg << 2) + j;
                    out[(size_t)row * DIM + col] = f2b(acc[ws][m][n][j] + bv_);
                }
        }
    }
    // ---- V epilogue: transpose via LDS T[128][129], then wave-contiguous
    //      1KB stores to Vt3[b][key/32][dv][key%32]
#pragma unroll
    for (int n = 0; n < 4; ++n) {
        const int dv = (wn << 6) + (n << 4) + l15;
        const float bv_ = bv[cbase + dv];
#pragma unroll
        for (int m = 0; m < 4; ++m)
#pragma unroll
            for (int j = 0; j < 4; ++j) {
                const int tok = (wm << 6) + (m << 4) + (lg << 2) + j;
                sm[tok * 129 + dv] = f2b(acc[2][m][n][j] + bv_);
            }
    }
    __syncthreads();
    {
        const int batch = rbase >> 13;
        const int c5_0  = (rbase & 8191) >> 5;   // key-chunk base (mult of 4)
#pragma unroll
        for (int s = 0; s < 8; ++s) {
            const int c5sel = s & 3, dvh = s >> 2;
            const int dvl  = (dvh << 6) + (wid << 4) + (lane >> 2);  // 0..127
            const int keyo = (lane & 3) << 3;                        // 0,8,16,24
            const int tok0 = (c5sel << 5) + keyo;
            u16x8 v;
#pragma unroll
            for (int j = 0; j < 8; ++j) v[j] = sm[(tok0 + j) * 129 + dvl];
            *(u16x8*)&vto[((size_t)((batch * 256 + c5_0 + c5sel) * 512
                                    + cbase + dvl) << 5) + keyo] = v;
        }
    }
}

// ===========================================================================
// Kernel 2: windowed attention (r12 form). grid = 512 x 512thr (8 waves).
// Wave w owns q-rows [w*16, w*16+16); Q in regs; K staged; V via Vt3.
// ===========================================================================
__global__ __launch_bounds__(512, 2) void k_attn(
    const unsigned short* __restrict__ q,
    const unsigned short* __restrict__ k,
    const unsigned short* __restrict__ vt3,
    float* __restrict__ out)
{
    __shared__ __align__(16) unsigned short Kb[32768];
    __shared__ __align__(16) unsigned short Pl[32768];

    int bid = (int)blockIdx.x;
    bid = (bid & 7) * 64 + (bid >> 3);    // XCD-chunked: one batch per XCD
    const int b = bid >> 6, w = bid & 63;
    const int tid  = threadIdx.x;
    const int lane = tid & 63, wid = tid >> 6;
    const int l15 = lane & 15, lg = lane >> 4;
    const int kstart = (w - 1) << 7;
    const size_t qrow0 = ((size_t)b << 13) + ((size_t)w << 7);
    const size_t kbase = (size_t)b << 13;

    const int srow = tid >> 3;            // 0..63
    const int s0   = tid & 7;

    // ---------------- Q-hoist: 16 bf16x8 frags -----------------------------
    bf16x8 qreg[16];
    {
        const unsigned short* qrp =
            &q[(qrow0 + (wid << 4) + l15) * DIM + (lg << 3)];
#pragma unroll
        for (int i = 0; i < 16; ++i)
            qreg[i] = *(const bf16x8*)&qrp[i << 5];
    }

    // ---------------- phase A: S = Q K^T (per-wave 16 x 256, inner 512) -----
    f32x4 acc[16];
#pragma unroll
    for (int n = 0; n < 16; ++n) acc[n] = (f32x4){0.f, 0.f, 0.f, 0.f};

    auto stageK = [&](int buf, int ds) {
#pragma unroll
        for (int i = 0; i < 4; ++i) {
            const int r = (i << 6) + srow;
            int krow = kstart + r; krow = krow < 0 ? 0 : krow;  // masked anyway
            gload_lds16(k + (kbase + krow) * DIM + (ds << 6) + ((s0 ^ (r & 7)) << 3),
                        Kb + (buf << 14) + (i << 12) + (tid << 3));
        }
    };

    stageK(0, 0);
    stageK(1, 1);
    __syncthreads();
#pragma unroll
    for (int ds = 0; ds < 8; ++ds) {
        const unsigned short* Kc = Kb + ((ds & 1) << 14);
#pragma unroll
        for (int kk2 = 0; kk2 < 2; ++kk2) {
            const int cu = (kk2 << 5) + (lg << 3);
            const bf16x8 af = qreg[(ds << 1) + kk2];   // static index (unrolled)
#pragma unroll
            for (int n = 0; n < 16; ++n) {
                const bf16x8 bf = *(const bf16x8*)&Kc[swz64((n << 4) + l15, cu)];
                acc[n] = __builtin_amdgcn_mfma_f32_16x16x32_bf16(af, bf, acc[n], 0, 0, 0);
            }
        }
        __syncthreads();
        if (ds + 2 < 8) stageK(ds & 1, ds + 2);  // 1-deep pipeline
    }

    // ---------------- phase B prologue: stage V chunks 0,1 (Kb free now) ----
    const int c5base = kstart >> 5;       // -4 for w==0
    auto stageV = [&](int buf, int kk) {
        int c5 = c5base + kk; c5 = c5 < 0 ? 0 : c5;  // P==0 for those keys
        const unsigned short* src = vt3 + ((size_t)(b * 256 + c5) << 14);
#pragma unroll
        for (int i = 0; i < 4; ++i)
            gload_lds16(src + (i << 12) + (tid << 3),
                        Kb + (buf << 14) + (i << 12) + (tid << 3));
    };
    stageV(0, 0);
    stageV(1, 1);

    // ---------------- per-wave masked softmax (no cross-wave barriers) ------
    const float scale = 0.04419417382415922f;  // 512^-0.5
    float inv[4];
    unsigned short* Pw = Pl + (wid << 12);     // wave-private [16][256] strip
#pragma unroll
    for (int jj = 0; jj < 4; ++jj) {
        const int r  = (lg << 2) + jj;         // wave-local q row
        const int qr = (wid << 4) + r;         // window q row
        float mx = -3.0e38f;
#pragma unroll
        for (int n = 0; n < 16; ++n) {
            const int c = (n << 4) + l15;
            const bool keep = (c <= qr + 128) && (w > 0 || c >= 128);
            const float s = keep ? acc[n][jj] * scale : -INFINITY;
            acc[n][jj] = s;
            mx = fmaxf(mx, s);
        }
#pragma unroll
        for (int o = 1; o < 16; o <<= 1) mx = fmaxf(mx, __shfl_xor(mx, o));
        float sum = 0.f;
#pragma unroll
        for (int n = 0; n < 16; ++n) {
            const float p = __expf(acc[n][jj] - mx);
            acc[n][jj] = p;
            sum += p;
        }
#pragma unroll
        for (int o = 1; o < 16; o <<= 1) sum += __shfl_xor(sum, o);
        inv[jj] = 1.0f / sum;                  // deferred normalization
#pragma unroll
        for (int n = 0; n < 16; ++n) {
            const int c = (n << 4) + l15;
            Pw[(r << 8) + ((((c >> 3) ^ r) << 3) | (c & 7))] = f2b(acc[n][jj]);
        }
    }
    __syncthreads();   // V chunks 0,1 staged; P strips written

    // ---------------- phase B: O = P V (per-wave 16 x 512, inner 256) -------
    f32x4 oacc[32];
#pragma unroll
    for (int n = 0; n < 32; ++n) oacc[n] = (f32x4){0.f, 0.f, 0.f, 0.f};

    for (int kk = 0; kk < 8; ++kk) {
        const unsigned short* Vc = Kb + ((kk & 1) << 14);
        const bf16x8 pa = *(const bf16x8*)
            &Pw[(l15 << 8) + ((((kk << 2) + lg) ^ l15) << 3)];
#pragma unroll
        for (int n = 0; n < 32; ++n) {
            const bf16x8 bv_ = *(const bf16x8*)&Vc[(((n << 4) + l15) << 5) + (lg << 3)];
            oacc[n] = __builtin_amdgcn_mfma_f32_16x16x32_bf16(pa, bv_, oacc[n], 0, 0, 0);
        }
        if (kk < 7) {
            __syncthreads();
            if (kk + 2 < 8) stageV(kk & 1, kk + 2);
        }
    }

    // ---------------- epilogue: normalize and store f32 ---------------------
#pragma unroll
    for (int n = 0; n < 32; ++n) {
        const int dv = (n << 4) + l15;
        float* orow = out + (qrow0 + (wid << 4) + (lg << 2)) * DIM + dv;
#pragma unroll
        for (int jj = 0; jj < 4; ++jj)
            orow[(size_t)jj * DIM] = oacc[n][jj] * inv[jj];
    }
}

// ===========================================================================
extern "C" void kernel_launch(void* const* d_in, const int* in_sizes, int n_in,
                              void* d_out, int out_size, void* d_ws, size_t ws_size,
                              hipStream_t stream) {
    (void)in_sizes; (void)n_in; (void)out_size; (void)ws_size;
    const float* x  = (const float*)d_in[0];
    const float* wq = (const float*)d_in[1];
    const float* bq = (const float*)d_in[2];
    const float* wk = (const float*)d_in[3];
    const float* bk = (const float*)d_in[4];
    const float* wv = (const float*)d_in[5];
    const float* bv = (const float*)d_in[6];
    float* out = (float*)d_out;

    unsigned short* qws  = (unsigned short*)d_ws;
    unsigned short* kws  = qws + WSELEM;
    unsigned short* vtws = kws + WSELEM;

    // xb (64 MiB) + wb (1.5 MiB) live in d_out (128 MiB) — consumed by k_qkv
    // before k_attn overwrites d_out with the final output (stream-ordered).
    unsigned short* xbuf = (unsigned short*)d_out;

    k_cvt<<<2048, 256, 0, stream>>>(x, wq, wk, wv, xbuf, NX8 + 3 * NW8);
    k_qkv<<<2048, 256, 0, stream>>>(xbuf, xbuf + WSELEM, bq, bk, bv,
                                    qws, kws, vtws);
    k_attn<<<512, 512, 0, stream>>>(qws, kws, vtws, out);
}